// Round 18
// baseline (47.544 us; speedup 1.0000x reference)
//
#include <hip/hip_runtime.h>
#include <hip/hip_bf16.h>

#define N_NODES 100000
#define N_EDGES 800000
#define D 64
#define SLICES 64                 // edge slices
#define QUARTERS 4                // node-range quarters
#define HIST_BLOCKS (SLICES * QUARTERS)  // 256 = full GPU
#define NQUART 25000              // nodes per quarter
#define HWORDS_Q 6272             // u8-packed words/quarter, padded to /4 (25 KB)
#define QUADS (N_EDGES / 4)       // 200000 quad-edge groups
#define QPS (QUADS / SLICES)      // 3125 quads per slice
#define XPAD 72                   // bf16 row stride: conflict-free frag reads

typedef __attribute__((ext_vector_type(8))) short bf16x8;
typedef __attribute__((ext_vector_type(4))) float f32x4;

// ---------------------------------------------------------------------------
// MEASUREMENT ROUND (R18): identical to R17 except hist_kernel is launched
// 5x (idempotent: each block fully rewrites its partial from zeroed LDS).
// H = (dur_us - 24.3) / 4. Replay-window algebra so far:
//   R12/R13: H+G = 13.3  (2-dispatch structure, consistent to 0.3)
//   R16/R17: P_mfma = 24.3 - 13.3 ~= 11.0 (floor ~9)  -> proj nearly done.
// The 13.3 splits unknown between hist and launch/graph overhead; the two
// possible next moves (cooperative fusion vs hist redesign) depend on it.
//
// softmax(axis=1) over [E,1] == 1.0 identically, so
//   z[n] = count[n] * (node_features[n] @ W_n^T + b_n)
// ---------------------------------------------------------------------------

__global__ __launch_bounds__(1024) void hist_kernel(
        const int* __restrict__ idx32,   // [2, N_EDGES] int64 or int32
        unsigned*  __restrict__ part) {  // [HIST_BLOCKS][HWORDS_Q]
    __shared__ __align__(16) unsigned h[HWORDS_Q];  // 25 KB, u8-packed
    uint4* __restrict__ h4 = (uint4*)h;
    for (int i = threadIdx.x; i < HWORDS_Q / 4; i += 1024)
        h4[i] = uint4{0u, 0u, 0u, 0u};

    // int64/int32 detection: for LE int64 values in [0,N_NODES) all odd
    // int32 words are 0. Each wave samples 256 odd words; ballot-OR.
    const int lane = threadIdx.x & 63;
    int s = 0;
#pragma unroll
    for (int k = 0; k < 4; ++k) s |= idx32[2 * (lane + 64 * k) + 1];
    const bool is64 = (__ballot(s != 0) == 0ULL);  // wave-uniform

    __syncthreads();

    const int slice = blockIdx.x >> 2;
    const int q     = blockIdx.x & 3;
    const int base  = q * NQUART;

    // 4 edges per iteration, vectorized loads. Count only our quarter-range.
    for (int t = slice * QPS + threadIdx.x; t < (slice + 1) * QPS; t += 1024) {
        int v[4];
        if (is64) {
            const int4 a = ((const int4*)idx32)[2 * t + 0];  // edges 4t,4t+1
            const int4 b = ((const int4*)idx32)[2 * t + 1];  // edges 4t+2,+3
            v[0] = a.x; v[1] = a.z; v[2] = b.x; v[3] = b.z;
        } else {
            const int4 a = ((const int4*)idx32)[t];
            v[0] = a.x; v[1] = a.y; v[2] = a.z; v[3] = a.w;
        }
#pragma unroll
        for (int j = 0; j < 4; ++j) {
            const unsigned u = (unsigned)(v[j] - base);
            if (u < (unsigned)NQUART)
                atomicAdd(&h[u >> 2], 1u << (8 * (u & 3)));  // LDS atomic
        }
    }

    __syncthreads();

    // stream partial to global, 16B stores (HWORDS_Q/4 = 1568 uint4)
    uint4* __restrict__ dst = (uint4*)(part + (size_t)blockIdx.x * HWORDS_Q);
    for (int i = threadIdx.x; i < HWORDS_Q / 4; i += 1024) dst[i] = h4[i];
}

// f32 -> bf16 (round-to-nearest-even), packed pair
__device__ inline unsigned bf16rn(float f) {
    const unsigned u = __float_as_uint(f);
    return (u + 0x7FFFu + ((u >> 16) & 1u)) >> 16;
}
__device__ inline unsigned pk2(float lo, float hi) {
    return bf16rn(lo) | (bf16rn(hi) << 16);
}

// Block = 256 threads = 4 waves; block handles 64 nodes (M=64), 64 outputs.
// Wave wv = m-tile (16 nodes); per wave: 4 n-tiles x 2 K-steps of
// mfma_f32_16x16x32_bf16. x,W live in LDS as bf16 [64][XPAD].
__global__ __launch_bounds__(256, 4) void proj_kernel(
        const float* __restrict__ nf,       // [N_NODES, 64]
        const float* __restrict__ Wn,       // [64, 64] row-major
        const float* __restrict__ bn,       // [64]
        const unsigned* __restrict__ part,  // [HIST_BLOCKS][HWORDS_Q]
        float* __restrict__ out) {          // [N_NODES, 64]
    __shared__ __align__(16) unsigned short xs[64 * XPAD];  // 9216 B
    __shared__ __align__(16) unsigned short wl[64 * XPAD];  // 9216 B
    __shared__ unsigned cnt_p[4][64];                       // merge-fold

    const int t = threadIdx.x;
    const int base = blockIdx.x * 64;
    const int lane = t & 63;
    const int wv = __builtin_amdgcn_readfirstlane(t >> 6);  // 0..3

    // ---- stage W: 4 threads/row, 16 f32 -> 16 bf16 each, 2 b128 writes ----
    {
        const int r = t >> 2;
        const int c0 = (t & 3) * 16;
        const float* __restrict__ src = Wn + r * D + c0;
        const float4 v0 = *reinterpret_cast<const float4*>(src + 0);
        const float4 v1 = *reinterpret_cast<const float4*>(src + 4);
        const float4 v2 = *reinterpret_cast<const float4*>(src + 8);
        const float4 v3 = *reinterpret_cast<const float4*>(src + 12);
        uint4 lo, hi;
        lo.x = pk2(v0.x, v0.y); lo.y = pk2(v0.z, v0.w);
        lo.z = pk2(v1.x, v1.y); lo.w = pk2(v1.z, v1.w);
        hi.x = pk2(v2.x, v2.y); hi.y = pk2(v2.z, v2.w);
        hi.z = pk2(v3.x, v3.y); hi.w = pk2(v3.z, v3.w);
        *reinterpret_cast<uint4*>(&wl[r * XPAD + c0 + 0]) = lo;
        *reinterpret_cast<uint4*>(&wl[r * XPAD + c0 + 8]) = hi;
    }

    // ---- stage x tile: same pattern, clamped tail rows ----
    {
        const int r = t >> 2;
        const int c0 = (t & 3) * 16;
        const int node = min(base + r, N_NODES - 1);
        const float* __restrict__ src = nf + (size_t)node * D + c0;
        const float4 v0 = *reinterpret_cast<const float4*>(src + 0);
        const float4 v1 = *reinterpret_cast<const float4*>(src + 4);
        const float4 v2 = *reinterpret_cast<const float4*>(src + 8);
        const float4 v3 = *reinterpret_cast<const float4*>(src + 12);
        uint4 lo, hi;
        lo.x = pk2(v0.x, v0.y); lo.y = pk2(v0.z, v0.w);
        lo.z = pk2(v1.x, v1.y); lo.w = pk2(v1.z, v1.w);
        hi.x = pk2(v2.x, v2.y); hi.y = pk2(v2.z, v2.w);
        hi.z = pk2(v3.x, v3.y); hi.w = pk2(v3.z, v3.w);
        *reinterpret_cast<uint4*>(&xs[r * XPAD + c0 + 0]) = lo;
        *reinterpret_cast<uint4*>(&xs[r * XPAD + c0 + 8]) = hi;
    }

    // ---- merge-fold: wave wv sums slice-partials [16wv,16wv+16) for its
    //      lane's node (clamped on tail; unused there). ----
    {
        const int node = min(base + lane, N_NODES - 1);
        const int q = node / NQUART;
        const int lw = (node - q * NQUART) >> 2;
        const int sh = 8 * (node & 3);
        unsigned s = 0;
#pragma unroll
        for (int k = 0; k < 16; ++k) {
            const int b = 16 * wv + k;  // slice
            s += (part[(size_t)(4 * b + q) * HWORDS_Q + lw] >> sh) & 255u;
        }
        cnt_p[wv][lane] = s;
    }

    __syncthreads();

    // ---- MFMA compute: m-tile = wv ----
    const int l15 = lane & 15;
    const int lhi = lane >> 4;  // 0..3

    // A frags: row = 16*wv + l15, k = ks*32 + lhi*8 + e
    const unsigned short* __restrict__ arow = &xs[(wv * 16 + l15) * XPAD + lhi * 8];
    const bf16x8 a0 = *reinterpret_cast<const bf16x8*>(arow + 0);
    const bf16x8 a1 = *reinterpret_cast<const bf16x8*>(arow + 32);

    // acc init = bias (depends only on output col) -> scale by count at store
    f32x4 acc[4];
#pragma unroll
    for (int nt = 0; nt < 4; ++nt) {
        const float b = bn[nt * 16 + l15];
        acc[nt] = f32x4{b, b, b, b};
    }

#pragma unroll
    for (int nt = 0; nt < 4; ++nt) {
        const unsigned short* __restrict__ brow =
            &wl[(nt * 16 + l15) * XPAD + lhi * 8];
        const bf16x8 b0 = *reinterpret_cast<const bf16x8*>(brow + 0);
        const bf16x8 b1 = *reinterpret_cast<const bf16x8*>(brow + 32);
        acc[nt] = __builtin_amdgcn_mfma_f32_16x16x32_bf16(a0, b0, acc[nt], 0, 0, 0);
        acc[nt] = __builtin_amdgcn_mfma_f32_16x16x32_bf16(a1, b1, acc[nt], 0, 0, 0);
    }

    // counts for this lane's 4 output rows: m = 16*wv + 4*lhi + r
    float cf[4];
#pragma unroll
    for (int r = 0; r < 4; ++r) {
        const int m = wv * 16 + lhi * 4 + r;
        cf[r] = (float)(cnt_p[0][m] + cnt_p[1][m] + cnt_p[2][m] + cnt_p[3][m]);
    }

    // store: D[m][n], m = 16*wv + 4*lhi + r, n = nt*16 + l15
#pragma unroll
    for (int nt = 0; nt < 4; ++nt) {
#pragma unroll
        for (int r = 0; r < 4; ++r) {
            const int node = base + wv * 16 + lhi * 4 + r;
            if (node < N_NODES)
                out[(size_t)node * D + nt * 16 + l15] = cf[r] * acc[nt][r];
        }
    }
}

extern "C" void kernel_launch(void* const* d_in, const int* in_sizes, int n_in,
                              void* d_out, int out_size, void* d_ws, size_t ws_size,
                              hipStream_t stream) {
    const float* nf   = (const float*)d_in[0];  // [100000, 64]
    const int*   eidx = (const int*)d_in[1];    // [2, 800000] int64 or int32
    const float* Wn   = (const float*)d_in[3];  // [64, 64]
    const float* bn   = (const float*)d_in[4];  // [64]
    float* out = (float*)d_out;                 // [100000, 64] f32

    unsigned* part = (unsigned*)d_ws;  // 256 x 25 KB = 6.42 MB slice-partials

    // AMPLIFICATION x5: identical, idempotent launches. H = (dur - 24.3)/4.
    for (int rep = 0; rep < 5; ++rep) {
        hist_kernel<<<HIST_BLOCKS, 1024, 0, stream>>>(eidx, part);
    }

    proj_kernel<<<(N_NODES + 63) / 64, 256, 0, stream>>>(
        nf, Wn, bn, part, out);
}

// Round 19
// 25.003 us; speedup vs baseline: 1.9015x; 1.9015x over previous
//
#include <hip/hip_runtime.h>
#include <hip/hip_bf16.h>

#define N_NODES 100000
#define N_EDGES 800000
#define D 64
#define SLICES 64                 // edge slices
#define QUARTERS 4                // node-range quarters
#define HIST_BLOCKS (SLICES * QUARTERS)  // 256 = full GPU
#define NQUART 25000              // nodes per quarter
#define HWORDS_Q 6272             // u8-packed words/quarter, padded to /4 (25 KB)
#define QUADS (N_EDGES / 4)       // 200000 quad-edge groups
#define QPS (QUADS / SLICES)      // 3125 quads per slice
#define XPAD 72                   // bf16 row stride: conflict-free frag reads

typedef __attribute__((ext_vector_type(8))) short bf16x8;
typedef __attribute__((ext_vector_type(4))) float f32x4;

// ---------------------------------------------------------------------------
// softmax(axis=1) over [E,1] == 1.0 identically, so
//   z[n] = count[n] * (node_features[n] @ W_n^T + b_n)
// where count[n] = #edges with node0_idx == n. Attention branch is dead code.
//
// Ledger (R18 measurements): total 24.3 = P 11.3 (BW floor ~9.1) +
// H 5.8 (floor ~2.5) + G ~7.2 (fixed graph/sync overhead; R3 showed
// marginal dispatch cost ~0.4us, so fusion buys nothing).
// R19: H's fat = cross-XCD idx re-fetch. blockIdx=slice*4+q round-robins
// quarter-siblings onto 4 DIFFERENT XCDs (xcd = blockIdx%8) -> idx slice
// fetched from HBM ~4x (25.6MB). Swizzle so all 4 quarters of a slice land
// on ONE XCD: slice data fetched once into that L2 (6.4MB total).
// ---------------------------------------------------------------------------

__global__ __launch_bounds__(1024) void hist_kernel(
        const int* __restrict__ idx32,   // [2, N_EDGES] int64 or int32
        unsigned*  __restrict__ part) {  // [SLICES*QUARTERS][HWORDS_Q]
    __shared__ __align__(16) unsigned h[HWORDS_Q];  // 25 KB, u8-packed
    uint4* __restrict__ h4 = (uint4*)h;
    for (int i = threadIdx.x; i < HWORDS_Q / 4; i += 1024)
        h4[i] = uint4{0u, 0u, 0u, 0u};

    // XCD-aware swizzle (heuristic, correctness-independent): XCD x hosts
    // slices [8x, 8x+8), each slice's 4 quarter-blocks on the SAME XCD ->
    // the slice's idx data is L2-resident after the first fetch.
    const int xcd = blockIdx.x & 7;
    const int i_  = blockIdx.x >> 3;          // 0..31
    const int slice = xcd * 8 + (i_ >> 2);    // 0..63
    const int q     = i_ & 3;                 // 0..3
    const int base  = q * NQUART;

    // int64/int32 detection: for LE int64 values in [0,N_NODES) all odd
    // int32 words are 0. Each wave samples 256 odd words; ballot-OR.
    const int lane = threadIdx.x & 63;
    int s = 0;
#pragma unroll
    for (int k = 0; k < 4; ++k) s |= idx32[2 * (lane + 64 * k) + 1];
    const bool is64 = (__ballot(s != 0) == 0ULL);  // wave-uniform

    __syncthreads();

    // 4 edges per iteration, vectorized loads. Count only our quarter-range.
    for (int t = slice * QPS + threadIdx.x; t < (slice + 1) * QPS; t += 1024) {
        int v[4];
        if (is64) {
            const int4 a = ((const int4*)idx32)[2 * t + 0];  // edges 4t,4t+1
            const int4 b = ((const int4*)idx32)[2 * t + 1];  // edges 4t+2,+3
            v[0] = a.x; v[1] = a.z; v[2] = b.x; v[3] = b.z;
        } else {
            const int4 a = ((const int4*)idx32)[t];
            v[0] = a.x; v[1] = a.y; v[2] = a.z; v[3] = a.w;
        }
#pragma unroll
        for (int j = 0; j < 4; ++j) {
            const unsigned u = (unsigned)(v[j] - base);
            if (u < (unsigned)NQUART)
                atomicAdd(&h[u >> 2], 1u << (8 * (u & 3)));  // LDS atomic
        }
    }

    __syncthreads();

    // stream partial to global at LOGICAL index (slice*4+q); proj unchanged.
    uint4* __restrict__ dst =
        (uint4*)(part + (size_t)(slice * QUARTERS + q) * HWORDS_Q);
    for (int i = threadIdx.x; i < HWORDS_Q / 4; i += 1024) dst[i] = h4[i];
}

// f32 -> bf16 (round-to-nearest-even), packed pair
__device__ inline unsigned bf16rn(float f) {
    const unsigned u = __float_as_uint(f);
    return (u + 0x7FFFu + ((u >> 16) & 1u)) >> 16;
}
__device__ inline unsigned pk2(float lo, float hi) {
    return bf16rn(lo) | (bf16rn(hi) << 16);
}

// Block = 256 threads = 4 waves; block handles 64 nodes (M=64), 64 outputs.
// Wave wv = m-tile (16 nodes); per wave: 4 n-tiles x 2 K-steps of
// mfma_f32_16x16x32_bf16. x,W live in LDS as bf16 [64][XPAD].
__global__ __launch_bounds__(256, 4) void proj_kernel(
        const float* __restrict__ nf,       // [N_NODES, 64]
        const float* __restrict__ Wn,       // [64, 64] row-major
        const float* __restrict__ bn,       // [64]
        const unsigned* __restrict__ part,  // [SLICES*QUARTERS][HWORDS_Q]
        float* __restrict__ out) {          // [N_NODES, 64]
    __shared__ __align__(16) unsigned short xs[64 * XPAD];  // 9216 B
    __shared__ __align__(16) unsigned short wl[64 * XPAD];  // 9216 B
    __shared__ unsigned cnt_p[4][64];                       // merge-fold

    const int t = threadIdx.x;
    const int base = blockIdx.x * 64;
    const int lane = t & 63;
    const int wv = __builtin_amdgcn_readfirstlane(t >> 6);  // 0..3

    // ---- stage W: 4 threads/row, 16 f32 -> 16 bf16 each, 2 b128 writes ----
    {
        const int r = t >> 2;
        const int c0 = (t & 3) * 16;
        const float* __restrict__ src = Wn + r * D + c0;
        const float4 v0 = *reinterpret_cast<const float4*>(src + 0);
        const float4 v1 = *reinterpret_cast<const float4*>(src + 4);
        const float4 v2 = *reinterpret_cast<const float4*>(src + 8);
        const float4 v3 = *reinterpret_cast<const float4*>(src + 12);
        uint4 lo, hi;
        lo.x = pk2(v0.x, v0.y); lo.y = pk2(v0.z, v0.w);
        lo.z = pk2(v1.x, v1.y); lo.w = pk2(v1.z, v1.w);
        hi.x = pk2(v2.x, v2.y); hi.y = pk2(v2.z, v2.w);
        hi.z = pk2(v3.x, v3.y); hi.w = pk2(v3.z, v3.w);
        *reinterpret_cast<uint4*>(&wl[r * XPAD + c0 + 0]) = lo;
        *reinterpret_cast<uint4*>(&wl[r * XPAD + c0 + 8]) = hi;
    }

    // ---- stage x tile: same pattern, clamped tail rows ----
    {
        const int r = t >> 2;
        const int c0 = (t & 3) * 16;
        const int node = min(base + r, N_NODES - 1);
        const float* __restrict__ src = nf + (size_t)node * D + c0;
        const float4 v0 = *reinterpret_cast<const float4*>(src + 0);
        const float4 v1 = *reinterpret_cast<const float4*>(src + 4);
        const float4 v2 = *reinterpret_cast<const float4*>(src + 8);
        const float4 v3 = *reinterpret_cast<const float4*>(src + 12);
        uint4 lo, hi;
        lo.x = pk2(v0.x, v0.y); lo.y = pk2(v0.z, v0.w);
        lo.z = pk2(v1.x, v1.y); lo.w = pk2(v1.z, v1.w);
        hi.x = pk2(v2.x, v2.y); hi.y = pk2(v2.z, v2.w);
        hi.z = pk2(v3.x, v3.y); hi.w = pk2(v3.z, v3.w);
        *reinterpret_cast<uint4*>(&xs[r * XPAD + c0 + 0]) = lo;
        *reinterpret_cast<uint4*>(&xs[r * XPAD + c0 + 8]) = hi;
    }

    // ---- merge-fold: wave wv sums slice-partials [16wv,16wv+16) for its
    //      lane's node (clamped on tail; unused there). ----
    {
        const int node = min(base + lane, N_NODES - 1);
        const int q = node / NQUART;
        const int lw = (node - q * NQUART) >> 2;
        const int sh = 8 * (node & 3);
        unsigned s = 0;
#pragma unroll
        for (int k = 0; k < 16; ++k) {
            const int b = 16 * wv + k;  // slice
            s += (part[(size_t)(4 * b + q) * HWORDS_Q + lw] >> sh) & 255u;
        }
        cnt_p[wv][lane] = s;
    }

    __syncthreads();

    // ---- MFMA compute: m-tile = wv ----
    const int l15 = lane & 15;
    const int lhi = lane >> 4;  // 0..3

    // A frags: row = 16*wv + l15, k = ks*32 + lhi*8 + e
    const unsigned short* __restrict__ arow = &xs[(wv * 16 + l15) * XPAD + lhi * 8];
    const bf16x8 a0 = *reinterpret_cast<const bf16x8*>(arow + 0);
    const bf16x8 a1 = *reinterpret_cast<const bf16x8*>(arow + 32);

    // acc init = bias (depends only on output col) -> scale by count at store
    f32x4 acc[4];
#pragma unroll
    for (int nt = 0; nt < 4; ++nt) {
        const float b = bn[nt * 16 + l15];
        acc[nt] = f32x4{b, b, b, b};
    }

#pragma unroll
    for (int nt = 0; nt < 4; ++nt) {
        const unsigned short* __restrict__ brow =
            &wl[(nt * 16 + l15) * XPAD + lhi * 8];
        const bf16x8 b0 = *reinterpret_cast<const bf16x8*>(brow + 0);
        const bf16x8 b1 = *reinterpret_cast<const bf16x8*>(brow + 32);
        acc[nt] = __builtin_amdgcn_mfma_f32_16x16x32_bf16(a0, b0, acc[nt], 0, 0, 0);
        acc[nt] = __builtin_amdgcn_mfma_f32_16x16x32_bf16(a1, b1, acc[nt], 0, 0, 0);
    }

    // counts for this lane's 4 output rows: m = 16*wv + 4*lhi + r
    float cf[4];
#pragma unroll
    for (int r = 0; r < 4; ++r) {
        const int m = wv * 16 + lhi * 4 + r;
        cf[r] = (float)(cnt_p[0][m] + cnt_p[1][m] + cnt_p[2][m] + cnt_p[3][m]);
    }

    // store: D[m][n], m = 16*wv + 4*lhi + r, n = nt*16 + l15
#pragma unroll
    for (int nt = 0; nt < 4; ++nt) {
#pragma unroll
        for (int r = 0; r < 4; ++r) {
            const int node = base + wv * 16 + lhi * 4 + r;
            if (node < N_NODES)
                out[(size_t)node * D + nt * 16 + l15] = cf[r] * acc[nt][r];
        }
    }
}

extern "C" void kernel_launch(void* const* d_in, const int* in_sizes, int n_in,
                              void* d_out, int out_size, void* d_ws, size_t ws_size,
                              hipStream_t stream) {
    const float* nf   = (const float*)d_in[0];  // [100000, 64]
    const int*   eidx = (const int*)d_in[1];    // [2, 800000] int64 or int32
    const float* Wn   = (const float*)d_in[3];  // [64, 64]
    const float* bn   = (const float*)d_in[4];  // [64]
    float* out = (float*)d_out;                 // [100000, 64] f32

    unsigned* part = (unsigned*)d_ws;  // 256 x 25 KB = 6.42 MB slice-partials

    hist_kernel<<<HIST_BLOCKS, 1024, 0, stream>>>(eidx, part);

    proj_kernel<<<(N_NODES + 63) / 64, 256, 0, stream>>>(
        nf, Wn, bn, part, out);
}